// Round 1
// baseline (219.409 us; speedup 1.0000x reference)
//
#include <hip/hip_runtime.h>
#include <hip/hip_fp16.h>

// Attention fused kernel for MI355X (gfx950).
// Pipeline: [conv h_i->f16] [conv W1->f16] [c = W2@h_t + b] ->
//           [f16 MFMA GEMM z=h@W1^T fused tanh*u reduce -> beta partials] ->
//           [softmax over 16384] -> [s = alpha@h_i two-stage reduce]
// ws layout (assumes ws_size >= ~36 MB):
//   h16   : 33,554,432 B @ 0
//   W16   :  2,097,152 B @ 33554432
//   c     :      4,096 B @ 35651584
//   betap :    524,288 B @ 35655680   (8 column-block partials x 16384)
//   alpha :     65,536 B @ 36179968
//   spart :  1,048,576 B @ 36245504   (256 partial s vectors x 1024)

#define L_ROWS 16384
#define D_DIM  1024
#define A_DIM  1024

typedef _Float16 f16;
typedef _Float16 f16x4 __attribute__((ext_vector_type(4)));
typedef _Float16 f16x8 __attribute__((ext_vector_type(8)));
typedef float    f32x4 __attribute__((ext_vector_type(4)));

// ---- async global->LDS, 16 B per lane (LDS dest = wave base + lane*16) ----
__device__ __forceinline__ void gload_lds16(const void* g, void* l) {
  __builtin_amdgcn_global_load_lds(
      (const __attribute__((address_space(1))) void*)g,
      (__attribute__((address_space(3))) void*)l,
      16, 0, 0);
}

// fast tanh: 1 - 2/(exp2(2x*log2e)+1); exact limits at +-inf
__device__ __forceinline__ float fast_tanh(float x) {
  float e = exp2f(x * 2.885390081777927f);
  return 1.0f - 2.0f * __builtin_amdgcn_rcpf(e + 1.0f);
}

// ---------------- conversions ----------------
__global__ void k_conv_h(const float* __restrict__ src, f16* __restrict__ dst) {
  const int idx = blockIdx.x * blockDim.x + threadIdx.x;   // one float4 each
  float4 v = reinterpret_cast<const float4*>(src)[idx];
  f16x4 o; o.x = (f16)v.x; o.y = (f16)v.y; o.z = (f16)v.z; o.w = (f16)v.w;
  reinterpret_cast<f16x4*>(dst)[idx] = o;
}

__global__ void k_conv_w(const float* __restrict__ Watt, f16* __restrict__ W16) {
  const int idx = blockIdx.x * blockDim.x + threadIdx.x;   // one float4 of W1
  const int a  = idx >> 8;        // 256 float4 per 1024-col row
  const int c4 = idx & 255;
  float4 v = reinterpret_cast<const float4*>(Watt)[(size_t)a * 512 + c4];
  f16x4 o; o.x = (f16)v.x; o.y = (f16)v.y; o.z = (f16)v.z; o.w = (f16)v.w;
  reinterpret_cast<f16x4*>(W16)[a * 256 + c4] = o;
}

// ---------------- c[a] = h_t . W2[a] + b[a]  (exact f32) ----------------
__global__ void k_c(const float* __restrict__ Watt, const float* __restrict__ ht,
                    const float* __restrict__ b, float* __restrict__ c) {
  const int a = blockIdx.x * 4 + (threadIdx.x >> 6);
  const int lane = threadIdx.x & 63;
  const float* row = Watt + (size_t)a * 2048 + 1024;
  float s = 0.f;
  #pragma unroll
  for (int d = lane; d < 1024; d += 64) s += row[d] * ht[d];
  #pragma unroll
  for (int off = 32; off; off >>= 1) s += __shfl_down(s, off);
  if (lane == 0) c[a] = s;
}

// ---------------- main fused GEMM ----------------
// 128x128 tile, BK=32, 4 waves (2x2), 16x16x32 f16 MFMA, m97 structure.
// Epilogue: beta_partial[colblock][row] = sum_a u[a]*tanh(z[row,a]+c[a])
__global__ __launch_bounds__(256, 3)
void k_gemm(const f16* __restrict__ H, const f16* __restrict__ W,
            const float* __restrict__ u, const float* __restrict__ c,
            float* __restrict__ betap) {
  __shared__ __align__(16) f16 As[128][32];
  __shared__ __align__(16) f16 Bs[128][32];
  __shared__ float red[128];

  const int tid  = threadIdx.x;
  const int bx   = blockIdx.x;            // col block 0..7 (fast -> stable XCD)
  const int by   = blockIdx.y;            // row block 0..127
  const int brow = by * 128;
  const int bcol = bx * 128;

  const int w    = tid >> 6;
  const int lane = tid & 63;
  const int wm   = w >> 1, wn = w & 1;
  const int lg   = lane >> 4;             // 0..3
  const int ll   = lane & 15;

  f32x4 acc[4][4] = {};

  // staging: 2 issues of 64 rows x 32 cols per tile (4 threads/row, 8 f16 each)
  const int srow = tid >> 2;
  const int scol = (tid & 3) * 8;
  const f16* gA = H + (size_t)(brow + srow) * D_DIM + scol;
  const f16* gB = W + (size_t)(bcol + srow) * D_DIM + scol;
  char* lA = (char*)(&As[0][0]) + tid * 16;
  char* lB = (char*)(&Bs[0][0]) + tid * 16;

  for (int kt = 0; kt < D_DIM / 32; ++kt) {
    const int ko = kt * 32;
    gload_lds16(gA + ko,              lA);
    gload_lds16(gA + ko + 64 * D_DIM, lA + 4096);
    gload_lds16(gB + ko,              lB);
    gload_lds16(gB + ko + 64 * D_DIM, lB + 4096);
    __syncthreads();   // drains vmcnt -> tiles resident

    f16x8 af[4], bf[4];
    #pragma unroll
    for (int m = 0; m < 4; ++m)
      af[m] = *(const f16x8*)&As[wm * 64 + m * 16 + ll][lg * 8];
    #pragma unroll
    for (int n = 0; n < 4; ++n)
      bf[n] = *(const f16x8*)&Bs[wn * 64 + n * 16 + ll][lg * 8];
    #pragma unroll
    for (int m = 0; m < 4; ++m)
      #pragma unroll
      for (int n = 0; n < 4; ++n)
        acc[m][n] = __builtin_amdgcn_mfma_f32_16x16x32_f16(af[m], bf[n], acc[m][n], 0, 0, 0);
    __syncthreads();   // compute done before next-tile overwrite
  }

  // epilogue: t = tanh(z + c[a]) * u[a]; reduce over this block's 128 columns
  float uv[4], cv[4];
  #pragma unroll
  for (int n = 0; n < 4; ++n) {
    const int a = bcol + wn * 64 + n * 16 + ll;
    uv[n] = u[a];
    cv[n] = c[a];
  }
  if (tid < 128) red[tid] = 0.f;
  __syncthreads();

  #pragma unroll
  for (int m = 0; m < 4; ++m) {
    float rs[4] = {0.f, 0.f, 0.f, 0.f};
    #pragma unroll
    for (int n = 0; n < 4; ++n) {
      #pragma unroll
      for (int r = 0; r < 4; ++r) {
        const float z = acc[m][n][r] + cv[n];
        rs[r] += fast_tanh(z) * uv[n];
      }
    }
    #pragma unroll
    for (int r = 0; r < 4; ++r) {
      float v = rs[r];
      v += __shfl_xor(v, 1);
      v += __shfl_xor(v, 2);
      v += __shfl_xor(v, 4);
      v += __shfl_xor(v, 8);
      if (ll == 0) atomicAdd(&red[wm * 64 + m * 16 + lg * 4 + r], v);
    }
  }
  __syncthreads();
  if (tid < 128) betap[(size_t)bx * L_ROWS + brow + tid] = red[tid];
}

// ---------------- softmax over 16384 (single WG) ----------------
__global__ __launch_bounds__(1024)
void k_softmax(const float* __restrict__ betap, float* __restrict__ alpha) {
  __shared__ float sred[32];
  const int t = threadIdx.x;
  float e[16];
  float mx = -3.0e38f;
  #pragma unroll
  for (int i = 0; i < 16; ++i) {
    const int l = t + i * 1024;
    float bsum = 0.f;
    #pragma unroll
    for (int j = 0; j < 8; ++j) bsum += betap[j * L_ROWS + l];
    e[i] = bsum;
    mx = fmaxf(mx, bsum);
  }
  #pragma unroll
  for (int off = 32; off; off >>= 1) mx = fmaxf(mx, __shfl_xor(mx, off));
  if ((t & 63) == 0) sred[t >> 6] = mx;
  __syncthreads();
  #pragma unroll
  for (int wv = 0; wv < 16; ++wv) mx = fmaxf(mx, sred[wv]);
  __syncthreads();
  float ssum = 0.f;
  #pragma unroll
  for (int i = 0; i < 16; ++i) {
    e[i] = expf(e[i] - mx);
    ssum += e[i];
  }
  #pragma unroll
  for (int off = 32; off; off >>= 1) ssum += __shfl_xor(ssum, off);
  if ((t & 63) == 0) sred[t >> 6] = ssum;
  __syncthreads();
  float tot = 0.f;
  #pragma unroll
  for (int wv = 0; wv < 16; ++wv) tot += sred[wv];
  const float rinv = 1.0f / tot;
  #pragma unroll
  for (int i = 0; i < 16; ++i) alpha[t + i * 1024] = e[i] * rinv;
}

// ---------------- s = alpha @ h_i (stage 1: 64-row partials) ----------------
__global__ __launch_bounds__(256)
void k_spart(const float* __restrict__ hi, const float* __restrict__ alpha,
             float* __restrict__ spart) {
  const int t  = threadIdx.x;   // col group: float4 t
  const int wg = blockIdx.x;    // 256 row chunks of 64
  const int r0 = wg * 64;
  float4 accv = make_float4(0.f, 0.f, 0.f, 0.f);
  const float4* hp = reinterpret_cast<const float4*>(hi + (size_t)r0 * D_DIM) + t;
  #pragma unroll 4
  for (int r = 0; r < 64; ++r) {
    const float a = alpha[r0 + r];
    float4 h = hp[r * 256];
    accv.x += a * h.x; accv.y += a * h.y; accv.z += a * h.z; accv.w += a * h.w;
  }
  reinterpret_cast<float4*>(spart + (size_t)wg * D_DIM)[t] = accv;
}

// ---------------- stage 2: reduce 256 partials ----------------
__global__ __launch_bounds__(256)
void k_sred(const float* __restrict__ spart, float* __restrict__ out) {
  const int col = blockIdx.x * 256 + threadIdx.x;
  float s = 0.f;
  for (int p = 0; p < 256; ++p) s += spart[p * D_DIM + col];
  out[col] = s;
}

extern "C" void kernel_launch(void* const* d_in, const int* in_sizes, int n_in,
                              void* d_out, int out_size, void* d_ws, size_t ws_size,
                              hipStream_t stream) {
  (void)in_sizes; (void)n_in; (void)out_size; (void)ws_size;
  const float* h_i = (const float*)d_in[0];
  const float* h_t = (const float*)d_in[1];
  const float* W   = (const float*)d_in[2];
  const float* b   = (const float*)d_in[3];
  const float* u   = (const float*)d_in[4];
  float* out = (float*)d_out;

  char* ws = (char*)d_ws;
  f16*   h16   = (f16*)ws;
  f16*   W16   = (f16*)(ws + 33554432);
  float* cvec  = (float*)(ws + 35651584);
  float* betap = (float*)(ws + 35655680);
  float* alpha = (float*)(ws + 36179968);
  float* spart = (float*)(ws + 36245504);

  k_conv_h<<<16384, 256, 0, stream>>>(h_i, h16);
  k_conv_w<<<1024, 256, 0, stream>>>(W, W16);
  k_c<<<256, 256, 0, stream>>>(W, h_t, b, cvec);
  k_gemm<<<dim3(8, 128), 256, 0, stream>>>(h16, W16, u, cvec, betap);
  k_softmax<<<1, 1024, 0, stream>>>(betap, alpha);
  k_spart<<<256, 256, 0, stream>>>(h_i, alpha, spart);
  k_sred<<<4, 256, 0, stream>>>(spart, out);
}

// Round 4
// 184.530 us; speedup vs baseline: 1.1890x; 1.1890x over previous
//
#include <hip/hip_runtime.h>
#include <hip/hip_fp16.h>

// Attention fused kernel for MI355X (gfx950).
// Pipeline: [conv h_i->f16] [conv W1->f16] [c = W2@h_t + b] ->
//           [f16 MFMA GEMM z=h@W1^T fused tanh*u reduce -> beta partials] ->
//           [k_smax: 16-block partial softmax stats + combined beta] ->
//           [k_spart: global softmax merge + alpha@h16 partials (1024 blocks)] ->
//           [k_sred: 64-block reduce -> s]
// ws layout (~38.6 MB):
//   h16   : 33,554,432 B @ 0
//   W16   :  2,097,152 B @ 33554432
//   c     :      4,096 B @ 35651584
//   betap :    524,288 B @ 35655680   (8 colblock partials x 16384)
//   beta  :     65,536 B @ 36179968   (combined beta)
//   stats :        128 B @ 36245504   (16 block maxes + 16 block sums)
//   spart :  4,194,304 B @ 36245632   (1024 partial s vectors x 1024)

#define L_ROWS 16384
#define D_DIM  1024
#define A_DIM  1024

typedef _Float16 f16;
typedef _Float16 f16x4 __attribute__((ext_vector_type(4)));
typedef _Float16 f16x8 __attribute__((ext_vector_type(8)));
typedef float    f32x4 __attribute__((ext_vector_type(4)));

// ---- async global->LDS, 16 B per lane (LDS dest = wave base + lane*16) ----
__device__ __forceinline__ void gload_lds16(const void* g, void* l) {
  __builtin_amdgcn_global_load_lds(
      (const __attribute__((address_space(1))) void*)g,
      (__attribute__((address_space(3))) void*)l,
      16, 0, 0);
}

// fast tanh: 1 - 2/(exp2(2x*log2e)+1); exact limits at +-inf
__device__ __forceinline__ float fast_tanh(float x) {
  float e = exp2f(x * 2.885390081777927f);
  return 1.0f - 2.0f * __builtin_amdgcn_rcpf(e + 1.0f);
}

// ---------------- conversions ----------------
__global__ __launch_bounds__(256)
void k_conv_h(const float* __restrict__ src, f16* __restrict__ dst) {
  const float4* s4 = reinterpret_cast<const float4*>(src);
  f16x4* d4 = reinterpret_cast<f16x4*>(dst);
  int i = blockIdx.x * 256 + threadIdx.x;          // 2048*256 threads, x8 stride
  #pragma unroll
  for (int it = 0; it < 8; ++it, i += 524288) {
    float4 v = s4[i];
    f16x4 o; o.x = (f16)v.x; o.y = (f16)v.y; o.z = (f16)v.z; o.w = (f16)v.w;
    d4[i] = o;
  }
}

__global__ __launch_bounds__(256)
void k_conv_w(const float* __restrict__ Watt, f16* __restrict__ W16) {
  const int idx = blockIdx.x * 256 + threadIdx.x;  // one float4 of W1
  const int a  = idx >> 8;                         // 256 float4 per 1024-col row
  const int c4 = idx & 255;
  float4 v = reinterpret_cast<const float4*>(Watt)[(size_t)a * 512 + c4];
  f16x4 o; o.x = (f16)v.x; o.y = (f16)v.y; o.z = (f16)v.z; o.w = (f16)v.w;
  reinterpret_cast<f16x4*>(W16)[a * 256 + c4] = o;
}

// ---------------- c[a] = h_t . W2[a] + b[a]  (exact f32) ----------------
__global__ __launch_bounds__(256)
void k_c(const float* __restrict__ Watt, const float* __restrict__ ht,
         const float* __restrict__ b, float* __restrict__ c) {
  const int a = blockIdx.x * 4 + (threadIdx.x >> 6);
  const int lane = threadIdx.x & 63;
  const float* row = Watt + (size_t)a * 2048 + 1024;
  float s = 0.f;
  #pragma unroll
  for (int d = lane; d < 1024; d += 64) s += row[d] * ht[d];
  #pragma unroll
  for (int off = 32; off; off >>= 1) s += __shfl_down(s, off);
  if (lane == 0) c[a] = b[a] + s;
}

// ---------------- main fused GEMM ----------------
// 128x128 tile, BK=32, 4 waves (2x2), 16x16x32 f16 MFMA, m97 structure.
// Grid dim3(128,8): rowblock fastest -> the 8 blocks sharing an A-panel get
// consecutive-by-128 linear ids == same id%8 -> same XCD -> A filled once/XCD.
__global__ __launch_bounds__(256, 3)
void k_gemm(const f16* __restrict__ H, const f16* __restrict__ W,
            const float* __restrict__ u, const float* __restrict__ c,
            float* __restrict__ betap) {
  __shared__ __align__(16) f16 As[128][32];
  __shared__ __align__(16) f16 Bs[128][32];
  __shared__ float red[128];

  const int tid  = threadIdx.x;
  const int brow = blockIdx.x * 128;      // 0..127 rowblocks (fast dim)
  const int bx   = blockIdx.y;            // 0..7 colblocks
  const int bcol = bx * 128;

  const int w    = tid >> 6;
  const int lane = tid & 63;
  const int wm   = w >> 1, wn = w & 1;
  const int lg   = lane >> 4;             // 0..3
  const int ll   = lane & 15;

  f32x4 acc[4][4] = {};

  // staging: 2 issues of 64 rows x 32 cols per tile (4 threads/row, 8 f16 each)
  const int srow = tid >> 2;
  const int scol = (tid & 3) * 8;
  const f16* gA = H + (size_t)(brow + srow) * D_DIM + scol;
  const f16* gB = W + (size_t)(bcol + srow) * D_DIM + scol;
  char* lA = (char*)(&As[0][0]) + tid * 16;
  char* lB = (char*)(&Bs[0][0]) + tid * 16;

  for (int kt = 0; kt < D_DIM / 32; ++kt) {
    const int ko = kt * 32;
    gload_lds16(gA + ko,              lA);
    gload_lds16(gA + ko + 64 * D_DIM, lA + 4096);
    gload_lds16(gB + ko,              lB);
    gload_lds16(gB + ko + 64 * D_DIM, lB + 4096);
    __syncthreads();   // drains vmcnt -> tiles resident

    f16x8 af[4], bf[4];
    #pragma unroll
    for (int m = 0; m < 4; ++m)
      af[m] = *(const f16x8*)&As[wm * 64 + m * 16 + ll][lg * 8];
    #pragma unroll
    for (int n = 0; n < 4; ++n)
      bf[n] = *(const f16x8*)&Bs[wn * 64 + n * 16 + ll][lg * 8];
    #pragma unroll
    for (int m = 0; m < 4; ++m)
      #pragma unroll
      for (int n = 0; n < 4; ++n)
        acc[m][n] = __builtin_amdgcn_mfma_f32_16x16x32_f16(af[m], bf[n], acc[m][n], 0, 0, 0);
    __syncthreads();   // compute done before next-tile overwrite
  }

  // epilogue: t = tanh(z + c[a]) * u[a]; reduce over this block's 128 columns
  float uv[4], cv[4];
  #pragma unroll
  for (int n = 0; n < 4; ++n) {
    const int a = bcol + wn * 64 + n * 16 + ll;
    uv[n] = u[a];
    cv[n] = c[a];
  }
  if (tid < 128) red[tid] = 0.f;
  __syncthreads();

  #pragma unroll
  for (int m = 0; m < 4; ++m) {
    float rs[4] = {0.f, 0.f, 0.f, 0.f};
    #pragma unroll
    for (int n = 0; n < 4; ++n) {
      #pragma unroll
      for (int r = 0; r < 4; ++r) {
        const float z = acc[m][n][r] + cv[n];
        rs[r] += fast_tanh(z) * uv[n];
      }
    }
    #pragma unroll
    for (int r = 0; r < 4; ++r) {
      float v = rs[r];
      v += __shfl_xor(v, 1);
      v += __shfl_xor(v, 2);
      v += __shfl_xor(v, 4);
      v += __shfl_xor(v, 8);
      if (ll == 0) atomicAdd(&red[wm * 64 + m * 16 + lg * 4 + r], v);
    }
  }
  __syncthreads();
  if (tid < 128) betap[(size_t)bx * L_ROWS + brow + tid] = red[tid];
}

// ---- partial softmax stats over 16 chunks of 1024 rows; write combined beta --
__global__ __launch_bounds__(1024)
void k_smax(const float* __restrict__ betap, float* __restrict__ beta,
            float* __restrict__ stats) {
  __shared__ float sred[16];
  const int t = threadIdx.x;
  const int r = blockIdx.x * 1024 + t;
  float bsum = 0.f;
  #pragma unroll
  for (int j = 0; j < 8; ++j) bsum += betap[j * L_ROWS + r];
  beta[r] = bsum;
  float mx = bsum;
  #pragma unroll
  for (int off = 32; off; off >>= 1) mx = fmaxf(mx, __shfl_xor(mx, off));
  if ((t & 63) == 0) sred[t >> 6] = mx;
  __syncthreads();
  float bm = sred[0];
  #pragma unroll
  for (int wv = 1; wv < 16; ++wv) bm = fmaxf(bm, sred[wv]);
  __syncthreads();
  float e = expf(bsum - bm);
  float s = e;
  #pragma unroll
  for (int off = 32; off; off >>= 1) s += __shfl_xor(s, off);
  if ((t & 63) == 0) sred[t >> 6] = s;
  __syncthreads();
  if (t == 0) {
    float tot = 0.f;
    #pragma unroll
    for (int wv = 0; wv < 16; ++wv) tot += sred[wv];
    stats[blockIdx.x] = bm;
    stats[16 + blockIdx.x] = tot;
  }
}

// ---- global softmax merge + s-partials: block = 16 rows, reads h16 (32MB) ---
__global__ __launch_bounds__(256)
void k_spart(const f16* __restrict__ h16, const float* __restrict__ beta,
             const float* __restrict__ stats, float* __restrict__ spart) {
  float gmax = stats[0];
  #pragma unroll
  for (int j = 1; j < 16; ++j) gmax = fmaxf(gmax, stats[j]);
  float gsum = 0.f;
  #pragma unroll
  for (int j = 0; j < 16; ++j) gsum += stats[16 + j] * expf(stats[j] - gmax);
  const float rg = 1.0f / gsum;

  const int t  = threadIdx.x;
  const int r0 = blockIdx.x * 16;
  float4 acc = make_float4(0.f, 0.f, 0.f, 0.f);
  const f16x4* hp = reinterpret_cast<const f16x4*>(h16 + (size_t)r0 * D_DIM) + t;
  #pragma unroll
  for (int r = 0; r < 16; ++r) {
    const float a = expf(beta[r0 + r] - gmax) * rg;
    f16x4 h = hp[r * 256];
    acc.x += a * (float)h.x; acc.y += a * (float)h.y;
    acc.z += a * (float)h.z; acc.w += a * (float)h.w;
  }
  reinterpret_cast<float4*>(spart + (size_t)blockIdx.x * D_DIM)[t] = acc;
}

// ---------------- reduce 1024 partial s vectors ----------------
__global__ __launch_bounds__(256)
void k_sred(const float* __restrict__ spart, float* __restrict__ out) {
  __shared__ float red[256];
  const int tid = threadIdx.x;
  const int c = tid & 15;               // col within block's 16
  const int g = tid >> 4;               // 16 partial-chunks
  const int col = blockIdx.x * 16 + c;
  float s = 0.f;
  #pragma unroll 8
  for (int p = g; p < 1024; p += 16) s += spart[(size_t)p * D_DIM + col];
  red[tid] = s;
  __syncthreads();
  if (tid < 16) {
    float tot = 0.f;
    #pragma unroll
    for (int g2 = 0; g2 < 16; ++g2) tot += red[g2 * 16 + tid];
    out[blockIdx.x * 16 + tid] = tot;
  }
}

extern "C" void kernel_launch(void* const* d_in, const int* in_sizes, int n_in,
                              void* d_out, int out_size, void* d_ws, size_t ws_size,
                              hipStream_t stream) {
  (void)in_sizes; (void)n_in; (void)out_size; (void)ws_size;
  const float* h_i = (const float*)d_in[0];
  const float* h_t = (const float*)d_in[1];
  const float* W   = (const float*)d_in[2];
  const float* b   = (const float*)d_in[3];
  const float* u   = (const float*)d_in[4];
  float* out = (float*)d_out;

  char* ws = (char*)d_ws;
  f16*   h16   = (f16*)ws;
  f16*   W16   = (f16*)(ws + 33554432);
  float* cvec  = (float*)(ws + 35651584);
  float* betap = (float*)(ws + 35655680);
  float* beta  = (float*)(ws + 36179968);
  float* stats = (float*)(ws + 36245504);
  float* spart = (float*)(ws + 36245632);

  k_conv_h<<<2048, 256, 0, stream>>>(h_i, h16);
  k_conv_w<<<1024, 256, 0, stream>>>(W, W16);
  k_c<<<256, 256, 0, stream>>>(W, h_t, b, cvec);
  k_gemm<<<dim3(128, 8), 256, 0, stream>>>(h16, W16, u, cvec, betap);
  k_smax<<<16, 1024, 0, stream>>>(betap, beta, stats);
  k_spart<<<1024, 256, 0, stream>>>(h16, beta, stats, spart);
  k_sred<<<64, 256, 0, stream>>>(spart, out);
}